// Round 6
// baseline (199.881 us; speedup 1.0000x reference)
//
#include <hip/hip_runtime.h>
#include <cstdint>
#include <cstddef>

typedef unsigned int u32;
typedef unsigned short u16;
typedef unsigned long long u64;

#define NBATCH 16
#define NA 9
#define HF 160
#define WF 160
#define HWC (HF*WF)          // 25600
#define NPB (NA*HWC)         // 230400 anchors per image
#define PRE_N 6000
#define POST_N 300
#define SEL_CAP 8192
#define NBIN 2048            // fallback radix bins
#define UNI_BINS 1024        // uniform score bins (2^10; s*1024 and q/1024 are exact fp32)
#define NMS_W 16             // waves in fused sort2+nms (1024 threads)
#define CHUNK 512            // sort1 chunk (16 chunks/img x 16 img = 256 blocks = full chip)

// [r4 lesson: do NOT fuse select into hist via done-ticket — the required
//  per-block __threadfence() (device-scope release = L2 writeback) executed by
//  all 720 blocks serialized the memory system: hist 40->110 us. This round's
//  select fusion instead RECOMPUTES the threshold redundantly per compact
//  block from the L2-resident hist — no fence, deterministic, identical.]
// [r1 lesson: never collapse a wide grid into the 16-block merge kernel.]

// Anchor constants derived exactly from generate_anchors(16,[0.5,1,2],[8,16,32]):
// all anchors have center (8,8) at cell (0,0); only w/h differ.
__constant__ float c_AW[9] = {184.f,368.f,736.f,128.f,256.f,512.f,88.f,176.f,352.f};
__constant__ float c_AH[9] = {96.f,192.f,384.f,128.f,256.f,512.f,176.f,352.f,704.f};

// Shared math core so the keep decision and box decode use byte-identical
// expressions (fp-contract applied identically).
__device__ __forceinline__ void box_core(
    float d0, float d1, float d2, float d3, int a, int x, int y,
    float imH, float imW, float ms,
    float& x1, float& y1, float& x2, float& y2, bool& keep)
{
  float aw = c_AW[a], ah = c_AH[a];
  float acx = (float)x * 16.0f + 8.0f;
  float acy = (float)y * 16.0f + 8.0f;
  float pcx = d0 * aw + acx;
  float pcy = d1 * ah + acy;
  float pw  = expf(d2) * aw;
  float ph  = expf(d3) * ah;
  x1 = fminf(fmaxf(pcx - 0.5f * pw, 0.0f), imW - 1.0f);
  y1 = fminf(fmaxf(pcy - 0.5f * ph, 0.0f), imH - 1.0f);
  x2 = fminf(fmaxf(pcx + 0.5f * pw, 0.0f), imW - 1.0f);
  y2 = fminf(fmaxf(pcy + 0.5f * ph, 0.0f), imH - 1.0f);
  keep = ((x2 - x1 + 1.0f) >= ms) && ((y2 - y1 + 1.0f) >= ms);
}

__device__ __forceinline__ void box_from_deltas(
    const float* __restrict__ bd, int b, int a, int pos,
    float imH, float imW, float ms,
    float& x1, float& y1, float& x2, float& y2, bool& keep)
{
  int y = pos / WF;
  int x = pos - y * WF;
  size_t base = ((size_t)(b * 4 * NA) + 4 * a) * HWC + (size_t)pos;
  float d0 = bd[base];
  float d1 = bd[base + HWC];
  float d2 = bd[base + 2 * HWC];
  float d3 = bd[base + 3 * HWC];
  box_core(d0, d1, d2, d3, a, x, y, imH, imW, ms, x1, y1, x2, y2, keep);
}

__device__ __forceinline__ u32 desc_enc(float s) {
  u32 su = __float_as_uint(s);
  u32 asc = (su & 0x80000000u) ? ~su : (su | 0x80000000u);
  return ~asc;
}

// Exact divide-free IoU>0.7 test: fmaf sign is exact outside a relative 1e-6
// band; inside the band fall back to the IEEE divide (same operand order as
// the reference), so the decision is bit-identical to the reference.
__device__ __forceinline__ bool iou_gt(float inter, float uni) {
  float ss = fmaf(0.7f, uni, -inter);
  if (fabsf(ss) <= uni * 1e-6f) return (inter / uni > 0.7f);
  return ss < 0.0f;
}

// keys (4B desc; flat idx derivable from array position) + fused single-pass
// uniform-bin histogram. r5: grid 3600 (16x9x25, 4 positions/thread, single
// pass) — the 720-block version ran at 34% occupancy (2.8 blocks/CU) and was
// latency-bound at ~2.2 TB/s; 3600 blocks fills the wave slots. UNI_BINS
// halved to 1024 to bound the per-block zero/flush overhead.
__global__ void __launch_bounds__(256) k_scores_hist(
    const float* __restrict__ sm, const float* __restrict__ bd,
    const float* __restrict__ info, u32* __restrict__ keys, u32* __restrict__ hist) {
  __shared__ u32 lh[UNI_BINS];
  int img   = blockIdx.x / 225;            // 225 = NA * 25
  int rem   = blockIdx.x - img * 225;
  int a     = rem / 25;
  int chunk = rem - a * 25;
  int tid = threadIdx.x;
  for (int i = tid; i < UNI_BINS; i += 256) lh[i] = 0;
  __syncthreads();
  float imH = info[img*3+0], imW = info[img*3+1], ms = 16.0f * info[img*3+2];
  const float* sp = sm + ((size_t)(img * 2 * NA) + NA + a) * HWC;
  const float* dp = bd + ((size_t)(img * 4 * NA) + 4 * a) * HWC;
  u32* kp = keys + (size_t)img * NPB + (size_t)a * HWC;
  int pos0 = (chunk * 256 + tid) * 4;
  float4 s4  = *(const float4*)&sp[pos0];
  float4 q0  = *(const float4*)&dp[pos0];
  float4 q1  = *(const float4*)&dp[HWC + pos0];
  float4 q2  = *(const float4*)&dp[2*HWC + pos0];
  float4 q3  = *(const float4*)&dp[3*HWC + pos0];
  float sv[4] = {s4.x, s4.y, s4.z, s4.w};
  float v0[4] = {q0.x, q0.y, q0.z, q0.w};
  float v1[4] = {q1.x, q1.y, q1.z, q1.w};
  float v2[4] = {q2.x, q2.y, q2.z, q2.w};
  float v3[4] = {q3.x, q3.y, q3.z, q3.w};
  u32 kq[4];
  #pragma unroll
  for (int e = 0; e < 4; e++) {
    int pos = pos0 + e;
    int y = pos / WF;
    int x = pos - y * WF;
    float x1, y1, x2, y2; bool keep;
    box_core(v0[e], v1[e], v2[e], v3[e], a, x, y, imH, imW, ms, x1, y1, x2, y2, keep);
    float s = sv[e];
    if (!keep) s = __uint_as_float(0xFF800000u);  // -inf
    kq[e] = desc_enc(s);
    int q = (int)floorf(s * (float)UNI_BINS);
    q = q < 0 ? 0 : (q > UNI_BINS - 1 ? UNI_BINS - 1 : q);
    atomicAdd(&lh[(UNI_BINS - 1) - q], 1u);
  }
  *(uint4*)&kp[pos0] = make_uint4(kq[0], kq[1], kq[2], kq[3]);
  __syncthreads();
  u32* gh = hist + img * UNI_BINS;
  for (int i = tid; i < UNI_BINS; i += 256) { u32 v = lh[i]; if (v) atomicAdd(&gh[i], v); }
}

// Compaction + box decode, with the threshold select FUSED in (r5): every
// block recomputes the threshold from the per-image hist (4 KB, L2-resident)
// — identical deterministic result in all 60 blocks, no fence, no extra
// dispatch. The block's 15 key loads are issued before the select scan so
// their latency hides under it. Radix fallback (pathological ties only)
// reads data ordered by the dispatch boundary.
// Sort element: [desc:32 (bits 62..31) | anchoridx:18 (30..13) | slot:13 (12..0)].
__global__ void __launch_bounds__(256) k_compact(
    const u32* __restrict__ keys, const u32* __restrict__ hist,
    u32* __restrict__ selcnt, u64* __restrict__ sel,
    const float* __restrict__ bd, const float* __restrict__ info,
    float4* __restrict__ boxsel) {
  __shared__ u32 sc[256];
  __shared__ u32 lh[NBIN];
  __shared__ u64 sh_thresh;
  __shared__ int sh_state;
  __shared__ u64 sh_prefix;
  __shared__ u32 sh_kth;
  __shared__ u32 sbase;
  int img = blockIdx.y;
  int tid = threadIdx.x;
  int t0 = blockIdx.x * 3840;
  const u32* kp = keys + (size_t)img * NPB + t0;
  // issue this block's key loads early (latency hides under the select scan)
  u32 dk[15];
  #pragma unroll
  for (int j = 0; j < 15; j++) dk[j] = kp[j * 256 + tid];
  // ---- inline select ----
  const u32* gh = hist + img * UNI_BINS;
  u32 loc[UNI_BINS / 256]; u32 tot = 0;
  #pragma unroll
  for (int j = 0; j < UNI_BINS / 256; j++) { loc[j] = gh[tid * (UNI_BINS / 256) + j]; tot += loc[j]; }
  if (tid == 0) { sh_state = 0; sh_prefix = 0; sh_kth = PRE_N; }
  sc[tid] = tot;
  __syncthreads();
  for (int off = 1; off < 256; off <<= 1) {
    u32 v = sc[tid]; u32 aa = (tid >= off) ? sc[tid - off] : 0u;
    __syncthreads(); sc[tid] = v + aa; __syncthreads();
  }
  u32 incl = sc[tid], excl = incl - tot;
  if (PRE_N > excl && PRE_N <= incl) {
    u32 run = excl;
    #pragma unroll
    for (int j = 0; j < UNI_BINS / 256; j++) {
      run += loc[j];
      if (run >= PRE_N) {
        int b = tid * (UNI_BINS / 256) + j;
        if (b < UNI_BINS - 1 && run <= SEL_CAP) {
          float sb = (float)(UNI_BINS - 1 - b) * (1.0f / (float)UNI_BINS);
          sh_thresh = ((u64)desc_enc(sb) << 32) | 0xFFFFFFFFull;
          sh_state = 1;
        }
        break;
      }
    }
  }
  __syncthreads();
  if (!sh_state) {
    const u32* kk = keys + (size_t)img * NPB;
    const int shifts[6] = {53, 42, 31, 20, 9, 0};
    const int widths[6] = {11, 11, 11, 11, 11, 9};
    for (int p = 0; p < 6; p++) {
      if (sh_state) break;
      for (int i = tid; i < NBIN; i += 256) lh[i] = 0;
      __syncthreads();
      u64 prefix = sh_prefix; u32 kth = sh_kth;
      int shift = shifts[p], width = widths[p];
      u32 nb = 1u << width;
      int hs = shift + width;
      for (int i = tid; i < NPB; i += 256) {
        int ia = i / HWC;
        int pos = i - ia * HWC;
        u64 key = ((u64)kk[i] << 32) | (u64)(u32)(pos * NA + ia);
        bool m = (p == 0) || ((key >> hs) == prefix);
        if (m) atomicAdd(&lh[(u32)(key >> shift) & (nb - 1u)], 1u);
      }
      __syncthreads();
      u32 l2[8]; u32 t2 = 0;
      #pragma unroll
      for (int j = 0; j < 8; j++) {
        u32 b = (u32)(tid * 8 + j);
        u32 v = (b < nb) ? lh[b] : 0u;
        l2[j] = v; t2 += v;
      }
      sc[tid] = t2; __syncthreads();
      for (int off = 1; off < 256; off <<= 1) {
        u32 v = sc[tid]; u32 aa = (tid >= off) ? sc[tid - off] : 0u;
        __syncthreads(); sc[tid] = v + aa; __syncthreads();
      }
      u32 incl2 = sc[tid], excl2 = incl2 - t2;
      if (kth > excl2 && kth <= incl2) {
        u32 run = excl2;
        for (int j = 0; j < 8; j++) {
          run += l2[j];
          if (run >= kth) {
            u32 bin = (u32)(tid * 8 + j);
            u32 below = run - l2[j];
            u32 cnt = l2[j];
            u32 knew = kth - below;
            u64 pfull = (prefix << width) | (u64)bin;
            u32 M = (u32)PRE_N - knew + cnt;
            if (M <= SEL_CAP) {
              u64 lowmask = (shift > 0) ? ((1ULL << shift) - 1ULL) : 0ULL;
              sh_thresh = (pfull << shift) | lowmask;
              sh_state = 1;
            } else {
              sh_prefix = pfull; sh_kth = knew;
            }
            break;
          }
        }
      }
      __syncthreads();
    }
  }
  __syncthreads();
  u64 T = sh_thresh;
  // ---- compaction ----
  u32 mycnt = 0;
  #pragma unroll
  for (int j = 0; j < 15; j++) {
    int t = t0 + j * 256 + tid;
    int a = t / HWC;
    int pos = t - a * HWC;
    u64 key = ((u64)dk[j] << 32) | (u64)(u32)(pos * NA + a);
    if (key <= T) mycnt++;
  }
  __syncthreads();                          // sc reuse after select
  sc[tid] = mycnt;
  __syncthreads();
  for (int off = 1; off < 256; off <<= 1) {
    u32 v = sc[tid];
    u32 add = (tid >= off) ? sc[tid - off] : 0u;
    __syncthreads();
    sc[tid] = v + add;
    __syncthreads();
  }
  if (tid == 255 && sc[255] > 0) sbase = atomicAdd(&selcnt[img], sc[255]);
  __syncthreads();
  if (mycnt == 0) return;
  u32 myoff = sbase + sc[tid] - mycnt;
  u64* sp = sel + (size_t)img * SEL_CAP;
  float4* bp = boxsel + (size_t)img * SEL_CAP;
  float imH = info[img*3+0], imW = info[img*3+1], ms = 16.0f * info[img*3+2];
  u32 c = 0;
  #pragma unroll
  for (int j = 0; j < 15; j++) {
    int t = t0 + j * 256 + tid;
    int a = t / HWC;
    int pos = t - a * HWC;
    u32 idx = (u32)(pos * NA + a);
    u64 key = ((u64)dk[j] << 32) | (u64)idx;
    if (key <= T) {
      u32 p = myoff + c;
      if (p < SEL_CAP) {
        u32 desc = dk[j];
        sp[p] = ((u64)desc << 31) | ((u64)idx << 13) | (u64)p;
        float x1, y1, x2, y2; bool keep;
        box_from_deltas(bd, img, a, pos, imH, imW, ms, x1, y1, x2, y2, keep);
        bp[p] = make_float4(x1, y1, x2, y2);
      }
      c++;
    }
  }
}

// Stage 1: sort each 512-key chunk ascending in LDS. 16 chunks/image x 16
// images = 256 blocks -> full-chip parallelism.
__global__ void __launch_bounds__(256) k_sort1(u64* __restrict__ sel, const u32* __restrict__ selcnt) {
  __shared__ u64 s[CHUNK];
  int img = blockIdx.y, c = blockIdx.x, tid = threadIdx.x;
  u32 cnt = selcnt[img]; if (cnt > SEL_CAP) cnt = SEL_CAP;
  u64* sp = sel + (size_t)img * SEL_CAP + (size_t)c * CHUNK;
  int gbase = c * CHUNK;
  for (int i = tid; i < CHUNK; i += 256) s[i] = ((u32)(gbase + i) < cnt) ? sp[i] : ~0ULL;
  __syncthreads();
  for (int k = 2; k <= CHUNK; k <<= 1) {
    for (int j = k >> 1; j > 0; j >>= 1) {
      for (int i = tid; i < CHUNK; i += 256) {
        int p = i ^ j;
        if (p > i) {
          u64 a = s[i], b = s[p];
          bool up = ((i & k) == 0);
          if (up ? (a > b) : (a < b)) { s[i] = b; s[p] = a; }
        }
      }
      __syncthreads();
    }
  }
  for (int i = tid; i < CHUNK; i += 256) sp[i] = s[i];
}

// Fused stage 2 + NMS (16 blocks x 1024 threads; fusion loses no parallelism).
// (a) final merge level prunes threads with d0 >= PRE_N (output unused);
// (b) phase-B Jacobi fixpoint == serial greedy (provably identical keep set);
// (c) wave-1 next-batch prefetch issued at phase-A start.
__global__ void __launch_bounds__(1024) k_sort2nms(
    const u64* __restrict__ sel, const u32* __restrict__ selcnt,
    const float4* __restrict__ boxsel, float* __restrict__ out) {
  union SB {
    u64 s[SEL_CAP];                        // 64 KiB (merge phase)
    struct {                               // NMS phase (~23 KiB, aliases s)
      u16 slot16[PRE_N + 64];              // rank -> boxsel slot (0xFFFF = invalid)
      float4 kbox[POST_N];
      float karea[POST_N];
      u64 kcodeW[(POST_N + 7) / 8];
      float4 cb[2][64];
      float car[2][64];
      int cint[2][64];
      u64 wcol[2][64];
      u64 supw[2][NMS_W];
    } n;
  };
  __shared__ SB u;
  __shared__ int sh_nv;
  __shared__ int sh_nkept;
  int img = blockIdx.x;
  int tid = threadIdx.x;
  const u64* sp = sel + (size_t)img * SEL_CAP;
  if (tid == 0) { sh_nv = PRE_N; sh_nkept = 0; }
  for (int i = tid; i < SEL_CAP; i += 1024) u.s[i] = sp[i];
  __syncthreads();
  // ---- merge 16 runs of 512 -> 8192 (4 merge-path levels) ----
  int d0 = tid * 8;
  for (int L = CHUNK; L < SEL_CAP; L <<= 1) {
    bool act = (2 * L < SEL_CAP) || (d0 < PRE_N);   // final-level prune
    u64 o[8];
    if (act) {
      int pairBase = d0 & ~(2 * L - 1);
      int d = d0 - pairBase;
      const u64* A = u.s + pairBase;
      const u64* B = u.s + pairBase + L;
      int lo = d - L; if (lo < 0) lo = 0;
      int hi = (d < L) ? d : L;
      while (lo < hi) {
        int mid = (lo + hi) >> 1;
        if (A[mid] <= B[d - 1 - mid]) lo = mid + 1; else hi = mid;
      }
      int ia = lo, ib = d - lo;
      #pragma unroll
      for (int k = 0; k < 8; k++) {
        bool ta = (ib >= L) || (ia < L && A[ia] <= B[ib]);
        o[k] = ta ? A[ia++] : B[ib++];
      }
    }
    __syncthreads();
    if (act) {
      #pragma unroll
      for (int k = 0; k < 8; k++) u.s[d0 + k] = o[k];
    }
    __syncthreads();
  }
  // ---- rank -> slot conversion (register-staged to dodge union aliasing) ----
  u64 rv[6];
  {
    int k = 0;
    for (int r = tid; r < PRE_N; r += 1024, k++) rv[k] = u.s[r];
    __syncthreads();                       // all s[] reads done before slot16 writes
    k = 0;
    for (int r = tid; r < PRE_N; r += 1024, k++) {
      u64 key = rv[k];
      u32 desc = (u32)(key >> 31);         // padding ~0 -> 0xFFFFFFFF
      bool valid = desc < 0xFF800000u;     // score > -inf
      if (!valid) atomicMin(&sh_nv, r);
      u.n.slot16[r] = valid ? (u16)(key & 0x1FFFu) : (u16)0xFFFF;
    }
  }
  __syncthreads();
  // ---- NMS ----
  int lane = tid & 63;
  int wv = tid >> 6;
  int nvalid = sh_nv;
  if (nvalid > PRE_N) nvalid = PRE_N;
  const float4* bp = boxsel + (size_t)img * SEL_CAP;
  if (tid < 64) {
    float4 c = make_float4(0.f, 0.f, 0.f, 0.f);
    if (tid < nvalid) { u16 sl = u.n.slot16[tid]; c = bp[sl]; }
    u.n.cb[0][tid] = c;
    float A = (c.z - c.x + 1.0f) * (c.w - c.y + 1.0f);
    u.n.car[0][tid] = A;
    u.n.cint[0][tid] = (int)rintf(8.0f * log2f(A));
  } else if (tid < 128) {
    u.n.wcol[0][tid - 64] = 0;
  } else if (tid < 128 + NMS_W) {
    u.n.supw[0][tid - 128] = 0;
  }
  __syncthreads();
  int pb = 0;
  for (int base = 0; base < nvalid; base += 64, pb ^= 1) {
    int nk = sh_nkept;
    if (nk >= POST_N) break;
    int bn = nvalid - base; if (bn > 64) bn = 64;
    // ---- wave-1: issue next-batch gather EARLY (hides under phase A+B) ----
    float4 pfc = make_float4(0.f, 0.f, 0.f, 0.f);
    bool havepf = (wv == 1) && (base + 64 < nvalid);
    if (havepf) {
      int i = base + 64 + lane;
      if (i < nvalid) { u16 sl = u.n.slot16[i]; pfc = bp[sl]; }
    }
    // ---- phase A: vs-kept tests + within-batch column masks (no early exit) ----
    bool sup;
    u64 colpart = 0;
    {
      bool inb = lane < bn;
      sup = !inb;
      if (inb) {
        float4 C = u.n.cb[pb][lane];
        float A0 = u.n.car[pb][lane];
        int myc = u.n.cint[pb][lane];
        int nw = (nk + 7) >> 3;
        for (int jw = wv; jw < nw; jw += NMS_W) {
          u64 w = u.n.kcodeW[jw];
          int jbase = jw << 3;
          int jm = nk - jbase; if (jm > 8) jm = 8;
          for (int k = 0; k < jm; k++) {
            int d = (int)((w >> (k * 8)) & 0xFFu) - myc;
            if (d > 5 || d < -5) continue;          // conservative area-ratio gate
            int j = jbase + k;
            float4 K = u.n.kbox[j];
            float xx1 = fmaxf(K.x, C.x);
            float yy1 = fmaxf(K.y, C.y);
            float xx2 = fminf(K.z, C.z);
            float yy2 = fminf(K.w, C.w);
            float iw = fmaxf(0.0f, xx2 - xx1 + 1.0f);
            float ih = fmaxf(0.0f, yy2 - yy1 + 1.0f);
            float inter = iw * ih;
            float uni = (u.n.karea[j] + A0) - inter; // kept area first (ref order)
            sup = sup | iou_gt(inter, uni);
          }
        }
        // within-batch: candidate = lane (the LATER one), scan earlier i
        for (int i = wv; i < lane; i += NMS_W) {
          if (i >= bn) break;
          float Ai = u.n.car[pb][i];
          if (Ai <= 0.6999f * A0 || A0 <= 0.6999f * Ai) continue;
          float4 I4 = u.n.cb[pb][i];
          float xx1 = fmaxf(I4.x, C.x);
          float yy1 = fmaxf(I4.y, C.y);
          float xx2 = fminf(I4.z, C.z);
          float yy2 = fminf(I4.w, C.w);
          float iw = fmaxf(0.0f, xx2 - xx1 + 1.0f);
          float ih = fmaxf(0.0f, yy2 - yy1 + 1.0f);
          float inter = iw * ih;
          float uni = (Ai + A0) - inter;            // earlier (i) area first
          if (iou_gt(inter, uni)) colpart |= 1ULL << i;
        }
      }
    }
    u64 bm = __ballot(sup);
    if (lane == 0) u.n.supw[pb][wv] = bm;
    if (colpart) atomicOr(&u.n.wcol[pb][lane], colpart);
    // wave-1: land prefetch into the other buffer (no reader until next iter)
    if (havepf) {
      u.n.cb[pb ^ 1][lane] = pfc;
      float A = (pfc.z - pfc.x + 1.0f) * (pfc.w - pfc.y + 1.0f);
      u.n.car[pb ^ 1][lane] = A;
      u.n.cint[pb ^ 1][lane] = (int)rintf(8.0f * log2f(A));
    }
    __syncthreads();
    // ---- phase B (wave 0: fixpoint greedy) | wave 2: zero next masks ----
    if (wv == 0) {
      u64 so = (lane < NMS_W) ? u.n.supw[pb][lane] : 0ULL;
      so |= __shfl_xor(so, 1);
      so |= __shfl_xor(so, 2);
      so |= __shfl_xor(so, 4);
      so |= __shfl_xor(so, 8);
      so = __shfl(so, 0);
      u64 validm = (bn >= 64) ? ~0ULL : ((1ULL << bn) - 1ULL);
      u64 colm = u.n.wcol[pb][lane];             // earlier-index suppressors of ME
      u64 live = validm & ~so;
      // Jacobi fixpoint == serial greedy (deps strictly earlier-index):
      // K_{t+1} = live & ~{c : K_t ∩ colm_c ≠ ∅}; converges in ≤ depth iters.
      u64 K = live;
      while (true) {
        u64 supk = __ballot((K & colm) != 0ULL);
        u64 Kn = live & ~supk;
        if (Kn == K) break;
        K = Kn;
      }
      int m = POST_N - nk;
      int kc = (int)__popcll(K);
      if (kc > m) {
        // greedy prefix property: first m keeps of the batch == greedy's m
        for (int e = kc - m; e > 0; --e) K &= ~(1ULL << (63 - __clzll((long long)K)));
        kc = m;
      }
      int cnt = nk + kc;
      if ((K >> lane) & 1ULL) {
        int rank = nk + (int)__popcll(K & ((1ULL << lane) - 1ULL));
        float4 C = u.n.cb[pb][lane];
        u.n.kbox[rank] = C;
        u.n.karea[rank] = u.n.car[pb][lane];
        ((unsigned char*)u.n.kcodeW)[rank] = (unsigned char)u.n.cint[pb][lane];
        float* o = out + ((size_t)img * POST_N + rank) * 5;
        o[0] = (float)img; o[1] = C.x; o[2] = C.y; o[3] = C.z; o[4] = C.w;
      }
      if (lane == 0) sh_nkept = cnt;
    } else if (wv == 2) {
      u.n.wcol[pb ^ 1][lane] = 0;
      if (lane < NMS_W) u.n.supw[pb ^ 1][lane] = 0;
    }
    __syncthreads();
  }
  int fk = sh_nkept;
  for (int r = fk + tid; r < POST_N; r += NMS_W * 64) {
    float* o = out + ((size_t)img * POST_N + r) * 5;
    o[0] = (float)img; o[1] = 0.f; o[2] = 0.f; o[3] = 0.f; o[4] = 0.f;
  }
}

extern "C" void kernel_launch(void* const* d_in, const int* in_sizes, int n_in,
                              void* d_out, int out_size, void* d_ws, size_t ws_size,
                              hipStream_t stream) {
  const float* sm   = (const float*)d_in[0];
  const float* bd   = (const float*)d_in[1];
  const float* info = (const float*)d_in[2];
  float* out = (float*)d_out;
  char* ws = (char*)d_ws;

  size_t off = 0;
  auto alloc = [&](size_t bytes) { size_t o = off; off += (bytes + 255) & ~(size_t)255; return o; };
  u32* keys     = (u32*)(ws + alloc((size_t)NBATCH * NPB * 4));        // ~14.7 MB
  size_t off_hist = alloc((size_t)NBATCH * UNI_BINS * 4);              // 64 KB
  u32* hist     = (u32*)(ws + off_hist);
  u32* selcnt   = (u32*)(ws + alloc(NBATCH * 4));                      // adjacent to hist
  size_t zero_end = off;
  u64* sel      = (u64*)(ws + alloc((size_t)NBATCH * SEL_CAP * 8));    // 1 MB
  float4* boxsel= (float4*)(ws + alloc((size_t)NBATCH * SEL_CAP * 16));// 2 MB
  (void)ws_size; (void)in_sizes; (void)n_in; (void)out_size;

  hipMemsetAsync(ws + off_hist, 0, zero_end - off_hist, stream);       // hist + selcnt
  hipLaunchKernelGGL(k_scores_hist, dim3(NBATCH * NA * 25), dim3(256), 0, stream, sm, bd, info, keys, hist);
  hipLaunchKernelGGL(k_compact, dim3(60, 16), dim3(256), 0, stream, keys, hist, selcnt, sel, bd, info, boxsel);
  hipLaunchKernelGGL(k_sort1, dim3(SEL_CAP / CHUNK, 16), dim3(256), 0, stream, sel, selcnt);
  hipLaunchKernelGGL(k_sort2nms, dim3(16), dim3(1024), 0, stream, sel, selcnt, boxsel, out);
}

// Round 7
// 195.357 us; speedup vs baseline: 1.0232x; 1.0232x over previous
//
#include <hip/hip_runtime.h>
#include <cstdint>
#include <cstddef>

typedef unsigned int u32;
typedef unsigned short u16;
typedef unsigned long long u64;

#define NBATCH 16
#define NA 9
#define HF 160
#define WF 160
#define HWC (HF*WF)          // 25600
#define NPB (NA*HWC)         // 230400 anchors per image
#define PRE_N 6000
#define POST_N 300
#define SEL_CAP 8192
#define NBIN 2048            // fallback radix bins
#define UNI_BINS 1024        // uniform score bins (2^10; s*1024 and q/1024 are exact fp32)
#define NMS_W 16             // waves in fused sort2+nms (1024 threads)
#define CHUNK 512            // sort1 chunk (16 chunks/img x 16 img = 256 blocks = full chip)

// [r6 lesson: hist at 3600 blocks (4 keys/thread) made the per-block LDS
//  zero+flush dominate (2048 LDS touches + ~640 global atomics per 1024 keys)
//  and doubled global hist atomics -> +18 us. 720 blocks (20 keys/thread) is
//  the right shape; occupancy was never hist's limiter.]
// [r4 lesson: do NOT fuse select into hist via done-ticket — per-block
//  __threadfence() (device-scope release = L2 writeback) x720 serialized the
//  memory system. Select is instead RECOMPUTED redundantly per compact block
//  from the L2-resident hist — no fence, deterministic, identical.]
// [r1 lesson: never collapse a wide grid into the 16-block merge kernel.]

// Anchor constants derived exactly from generate_anchors(16,[0.5,1,2],[8,16,32]):
// all anchors have center (8,8) at cell (0,0); only w/h differ.
__constant__ float c_AW[9] = {184.f,368.f,736.f,128.f,256.f,512.f,88.f,176.f,352.f};
__constant__ float c_AH[9] = {96.f,192.f,384.f,128.f,256.f,512.f,176.f,352.f,704.f};

// Shared math core so the keep decision and box decode use byte-identical
// expressions (fp-contract applied identically).
__device__ __forceinline__ void box_core(
    float d0, float d1, float d2, float d3, int a, int x, int y,
    float imH, float imW, float ms,
    float& x1, float& y1, float& x2, float& y2, bool& keep)
{
  float aw = c_AW[a], ah = c_AH[a];
  float acx = (float)x * 16.0f + 8.0f;
  float acy = (float)y * 16.0f + 8.0f;
  float pcx = d0 * aw + acx;
  float pcy = d1 * ah + acy;
  float pw  = expf(d2) * aw;
  float ph  = expf(d3) * ah;
  x1 = fminf(fmaxf(pcx - 0.5f * pw, 0.0f), imW - 1.0f);
  y1 = fminf(fmaxf(pcy - 0.5f * ph, 0.0f), imH - 1.0f);
  x2 = fminf(fmaxf(pcx + 0.5f * pw, 0.0f), imW - 1.0f);
  y2 = fminf(fmaxf(pcy + 0.5f * ph, 0.0f), imH - 1.0f);
  keep = ((x2 - x1 + 1.0f) >= ms) && ((y2 - y1 + 1.0f) >= ms);
}

__device__ __forceinline__ void box_from_deltas(
    const float* __restrict__ bd, int b, int a, int pos,
    float imH, float imW, float ms,
    float& x1, float& y1, float& x2, float& y2, bool& keep)
{
  int y = pos / WF;
  int x = pos - y * WF;
  size_t base = ((size_t)(b * 4 * NA) + 4 * a) * HWC + (size_t)pos;
  float d0 = bd[base];
  float d1 = bd[base + HWC];
  float d2 = bd[base + 2 * HWC];
  float d3 = bd[base + 3 * HWC];
  box_core(d0, d1, d2, d3, a, x, y, imH, imW, ms, x1, y1, x2, y2, keep);
}

__device__ __forceinline__ u32 desc_enc(float s) {
  u32 su = __float_as_uint(s);
  u32 asc = (su & 0x80000000u) ? ~su : (su | 0x80000000u);
  return ~asc;
}

// Exact divide-free IoU>0.7 test: fmaf sign is exact outside a relative 1e-6
// band; inside the band fall back to the IEEE divide (same operand order as
// the reference), so the decision is bit-identical to the reference.
__device__ __forceinline__ bool iou_gt(float inter, float uni) {
  float ss = fmaf(0.7f, uni, -inter);
  if (fabsf(ss) <= uni * 1e-6f) return (inter / uni > 0.7f);
  return ss < 0.0f;
}

// keys (4B desc; flat idx derivable from array position) + fused single-pass
// uniform-bin histogram. 720 blocks x 20 keys/thread (proven shape);
// UNI_BINS=1024 halves the per-block zero/flush overhead vs 2048.
__global__ void __launch_bounds__(256) k_scores_hist(
    const float* __restrict__ sm, const float* __restrict__ bd,
    const float* __restrict__ info, u32* __restrict__ keys, u32* __restrict__ hist) {
  __shared__ u32 lh[UNI_BINS];
  int img   = blockIdx.x / 45;
  int rem   = blockIdx.x - img * 45;
  int a     = rem / 5;
  int chunk = rem - a * 5;
  int tid = threadIdx.x;
  for (int i = tid; i < UNI_BINS; i += 256) lh[i] = 0;
  __syncthreads();
  float imH = info[img*3+0], imW = info[img*3+1], ms = 16.0f * info[img*3+2];
  const float* sp = sm + ((size_t)(img * 2 * NA) + NA + a) * HWC;
  const float* dp = bd + ((size_t)(img * 4 * NA) + 4 * a) * HWC;
  u32* kp = keys + (size_t)img * NPB + (size_t)a * HWC;
  for (int j = 0; j < 5; j++) {
    int pos0 = (chunk * 1280 + j * 256 + tid) * 4;
    float4 s4  = *(const float4*)&sp[pos0];
    float4 q0  = *(const float4*)&dp[pos0];
    float4 q1  = *(const float4*)&dp[HWC + pos0];
    float4 q2  = *(const float4*)&dp[2*HWC + pos0];
    float4 q3  = *(const float4*)&dp[3*HWC + pos0];
    float sv[4] = {s4.x, s4.y, s4.z, s4.w};
    float v0[4] = {q0.x, q0.y, q0.z, q0.w};
    float v1[4] = {q1.x, q1.y, q1.z, q1.w};
    float v2[4] = {q2.x, q2.y, q2.z, q2.w};
    float v3[4] = {q3.x, q3.y, q3.z, q3.w};
    u32 kq[4];
    #pragma unroll
    for (int e = 0; e < 4; e++) {
      int pos = pos0 + e;
      int y = pos / WF;
      int x = pos - y * WF;
      float x1, y1, x2, y2; bool keep;
      box_core(v0[e], v1[e], v2[e], v3[e], a, x, y, imH, imW, ms, x1, y1, x2, y2, keep);
      float s = sv[e];
      if (!keep) s = __uint_as_float(0xFF800000u);  // -inf
      kq[e] = desc_enc(s);
      int q = (int)floorf(s * (float)UNI_BINS);
      q = q < 0 ? 0 : (q > UNI_BINS - 1 ? UNI_BINS - 1 : q);
      atomicAdd(&lh[(UNI_BINS - 1) - q], 1u);
    }
    *(uint4*)&kp[pos0] = make_uint4(kq[0], kq[1], kq[2], kq[3]);
  }
  __syncthreads();
  u32* gh = hist + img * UNI_BINS;
  for (int i = tid; i < UNI_BINS; i += 256) { u32 v = lh[i]; if (v) atomicAdd(&gh[i], v); }
}

// Compaction + box decode, with the threshold select FUSED in: every block
// recomputes the threshold from the per-image hist (4 KB, L2-resident) —
// identical deterministic result in all 60 blocks, no fence, no extra
// dispatch. The block's 15 key loads are issued before the select scan so
// their latency hides under it. Radix fallback (pathological ties only)
// reads data ordered by the dispatch boundary.
// Sort element: [desc:32 (bits 62..31) | anchoridx:18 (30..13) | slot:13 (12..0)].
__global__ void __launch_bounds__(256) k_compact(
    const u32* __restrict__ keys, const u32* __restrict__ hist,
    u32* __restrict__ selcnt, u64* __restrict__ sel,
    const float* __restrict__ bd, const float* __restrict__ info,
    float4* __restrict__ boxsel) {
  __shared__ u32 sc[256];
  __shared__ u32 lh[NBIN];
  __shared__ u64 sh_thresh;
  __shared__ int sh_state;
  __shared__ u64 sh_prefix;
  __shared__ u32 sh_kth;
  __shared__ u32 sbase;
  int img = blockIdx.y;
  int tid = threadIdx.x;
  int t0 = blockIdx.x * 3840;
  const u32* kp = keys + (size_t)img * NPB + t0;
  // issue this block's key loads early (latency hides under the select scan)
  u32 dk[15];
  #pragma unroll
  for (int j = 0; j < 15; j++) dk[j] = kp[j * 256 + tid];
  // ---- inline select ----
  const u32* gh = hist + img * UNI_BINS;
  u32 loc[UNI_BINS / 256]; u32 tot = 0;
  #pragma unroll
  for (int j = 0; j < UNI_BINS / 256; j++) { loc[j] = gh[tid * (UNI_BINS / 256) + j]; tot += loc[j]; }
  if (tid == 0) { sh_state = 0; sh_prefix = 0; sh_kth = PRE_N; }
  sc[tid] = tot;
  __syncthreads();
  for (int off = 1; off < 256; off <<= 1) {
    u32 v = sc[tid]; u32 aa = (tid >= off) ? sc[tid - off] : 0u;
    __syncthreads(); sc[tid] = v + aa; __syncthreads();
  }
  u32 incl = sc[tid], excl = incl - tot;
  if (PRE_N > excl && PRE_N <= incl) {
    u32 run = excl;
    #pragma unroll
    for (int j = 0; j < UNI_BINS / 256; j++) {
      run += loc[j];
      if (run >= PRE_N) {
        int b = tid * (UNI_BINS / 256) + j;
        if (b < UNI_BINS - 1 && run <= SEL_CAP) {
          float sb = (float)(UNI_BINS - 1 - b) * (1.0f / (float)UNI_BINS);
          sh_thresh = ((u64)desc_enc(sb) << 32) | 0xFFFFFFFFull;
          sh_state = 1;
        }
        break;
      }
    }
  }
  __syncthreads();
  if (!sh_state) {
    const u32* kk = keys + (size_t)img * NPB;
    const int shifts[6] = {53, 42, 31, 20, 9, 0};
    const int widths[6] = {11, 11, 11, 11, 11, 9};
    for (int p = 0; p < 6; p++) {
      if (sh_state) break;
      for (int i = tid; i < NBIN; i += 256) lh[i] = 0;
      __syncthreads();
      u64 prefix = sh_prefix; u32 kth = sh_kth;
      int shift = shifts[p], width = widths[p];
      u32 nb = 1u << width;
      int hs = shift + width;
      for (int i = tid; i < NPB; i += 256) {
        int ia = i / HWC;
        int pos = i - ia * HWC;
        u64 key = ((u64)kk[i] << 32) | (u64)(u32)(pos * NA + ia);
        bool m = (p == 0) || ((key >> hs) == prefix);
        if (m) atomicAdd(&lh[(u32)(key >> shift) & (nb - 1u)], 1u);
      }
      __syncthreads();
      u32 l2[8]; u32 t2 = 0;
      #pragma unroll
      for (int j = 0; j < 8; j++) {
        u32 b = (u32)(tid * 8 + j);
        u32 v = (b < nb) ? lh[b] : 0u;
        l2[j] = v; t2 += v;
      }
      sc[tid] = t2; __syncthreads();
      for (int off = 1; off < 256; off <<= 1) {
        u32 v = sc[tid]; u32 aa = (tid >= off) ? sc[tid - off] : 0u;
        __syncthreads(); sc[tid] = v + aa; __syncthreads();
      }
      u32 incl2 = sc[tid], excl2 = incl2 - t2;
      if (kth > excl2 && kth <= incl2) {
        u32 run = excl2;
        for (int j = 0; j < 8; j++) {
          run += l2[j];
          if (run >= kth) {
            u32 bin = (u32)(tid * 8 + j);
            u32 below = run - l2[j];
            u32 cnt = l2[j];
            u32 knew = kth - below;
            u64 pfull = (prefix << width) | (u64)bin;
            u32 M = (u32)PRE_N - knew + cnt;
            if (M <= SEL_CAP) {
              u64 lowmask = (shift > 0) ? ((1ULL << shift) - 1ULL) : 0ULL;
              sh_thresh = (pfull << shift) | lowmask;
              sh_state = 1;
            } else {
              sh_prefix = pfull; sh_kth = knew;
            }
            break;
          }
        }
      }
      __syncthreads();
    }
  }
  __syncthreads();
  u64 T = sh_thresh;
  // ---- compaction ----
  u32 mycnt = 0;
  #pragma unroll
  for (int j = 0; j < 15; j++) {
    int t = t0 + j * 256 + tid;
    int a = t / HWC;
    int pos = t - a * HWC;
    u64 key = ((u64)dk[j] << 32) | (u64)(u32)(pos * NA + a);
    if (key <= T) mycnt++;
  }
  __syncthreads();                          // sc reuse after select
  sc[tid] = mycnt;
  __syncthreads();
  for (int off = 1; off < 256; off <<= 1) {
    u32 v = sc[tid];
    u32 add = (tid >= off) ? sc[tid - off] : 0u;
    __syncthreads();
    sc[tid] = v + add;
    __syncthreads();
  }
  if (tid == 255 && sc[255] > 0) sbase = atomicAdd(&selcnt[img], sc[255]);
  __syncthreads();
  if (mycnt == 0) return;
  u32 myoff = sbase + sc[tid] - mycnt;
  u64* sp = sel + (size_t)img * SEL_CAP;
  float4* bp = boxsel + (size_t)img * SEL_CAP;
  float imH = info[img*3+0], imW = info[img*3+1], ms = 16.0f * info[img*3+2];
  u32 c = 0;
  #pragma unroll
  for (int j = 0; j < 15; j++) {
    int t = t0 + j * 256 + tid;
    int a = t / HWC;
    int pos = t - a * HWC;
    u32 idx = (u32)(pos * NA + a);
    u64 key = ((u64)dk[j] << 32) | (u64)idx;
    if (key <= T) {
      u32 p = myoff + c;
      if (p < SEL_CAP) {
        u32 desc = dk[j];
        sp[p] = ((u64)desc << 31) | ((u64)idx << 13) | (u64)p;
        float x1, y1, x2, y2; bool keep;
        box_from_deltas(bd, img, a, pos, imH, imW, ms, x1, y1, x2, y2, keep);
        bp[p] = make_float4(x1, y1, x2, y2);
      }
      c++;
    }
  }
}

// Stage 1: sort each 512-key chunk ascending in LDS. 16 chunks/image x 16
// images = 256 blocks -> full-chip parallelism.
__global__ void __launch_bounds__(256) k_sort1(u64* __restrict__ sel, const u32* __restrict__ selcnt) {
  __shared__ u64 s[CHUNK];
  int img = blockIdx.y, c = blockIdx.x, tid = threadIdx.x;
  u32 cnt = selcnt[img]; if (cnt > SEL_CAP) cnt = SEL_CAP;
  u64* sp = sel + (size_t)img * SEL_CAP + (size_t)c * CHUNK;
  int gbase = c * CHUNK;
  for (int i = tid; i < CHUNK; i += 256) s[i] = ((u32)(gbase + i) < cnt) ? sp[i] : ~0ULL;
  __syncthreads();
  for (int k = 2; k <= CHUNK; k <<= 1) {
    for (int j = k >> 1; j > 0; j >>= 1) {
      for (int i = tid; i < CHUNK; i += 256) {
        int p = i ^ j;
        if (p > i) {
          u64 a = s[i], b = s[p];
          bool up = ((i & k) == 0);
          if (up ? (a > b) : (a < b)) { s[i] = b; s[p] = a; }
        }
      }
      __syncthreads();
    }
  }
  for (int i = tid; i < CHUNK; i += 256) sp[i] = s[i];
}

// Fused stage 2 + NMS (16 blocks x 1024 threads; fusion loses no parallelism).
// (a) final merge level prunes threads with d0 >= PRE_N (output unused);
// (b) phase-B Jacobi fixpoint == serial greedy (provably identical keep set);
// (c) wave-1 next-batch prefetch issued at phase-A start.
__global__ void __launch_bounds__(1024) k_sort2nms(
    const u64* __restrict__ sel, const u32* __restrict__ selcnt,
    const float4* __restrict__ boxsel, float* __restrict__ out) {
  union SB {
    u64 s[SEL_CAP];                        // 64 KiB (merge phase)
    struct {                               // NMS phase (~23 KiB, aliases s)
      u16 slot16[PRE_N + 64];              // rank -> boxsel slot (0xFFFF = invalid)
      float4 kbox[POST_N];
      float karea[POST_N];
      u64 kcodeW[(POST_N + 7) / 8];
      float4 cb[2][64];
      float car[2][64];
      int cint[2][64];
      u64 wcol[2][64];
      u64 supw[2][NMS_W];
    } n;
  };
  __shared__ SB u;
  __shared__ int sh_nv;
  __shared__ int sh_nkept;
  int img = blockIdx.x;
  int tid = threadIdx.x;
  const u64* sp = sel + (size_t)img * SEL_CAP;
  if (tid == 0) { sh_nv = PRE_N; sh_nkept = 0; }
  for (int i = tid; i < SEL_CAP; i += 1024) u.s[i] = sp[i];
  __syncthreads();
  // ---- merge 16 runs of 512 -> 8192 (4 merge-path levels) ----
  int d0 = tid * 8;
  for (int L = CHUNK; L < SEL_CAP; L <<= 1) {
    bool act = (2 * L < SEL_CAP) || (d0 < PRE_N);   // final-level prune
    u64 o[8];
    if (act) {
      int pairBase = d0 & ~(2 * L - 1);
      int d = d0 - pairBase;
      const u64* A = u.s + pairBase;
      const u64* B = u.s + pairBase + L;
      int lo = d - L; if (lo < 0) lo = 0;
      int hi = (d < L) ? d : L;
      while (lo < hi) {
        int mid = (lo + hi) >> 1;
        if (A[mid] <= B[d - 1 - mid]) lo = mid + 1; else hi = mid;
      }
      int ia = lo, ib = d - lo;
      #pragma unroll
      for (int k = 0; k < 8; k++) {
        bool ta = (ib >= L) || (ia < L && A[ia] <= B[ib]);
        o[k] = ta ? A[ia++] : B[ib++];
      }
    }
    __syncthreads();
    if (act) {
      #pragma unroll
      for (int k = 0; k < 8; k++) u.s[d0 + k] = o[k];
    }
    __syncthreads();
  }
  // ---- rank -> slot conversion (register-staged to dodge union aliasing) ----
  u64 rv[6];
  {
    int k = 0;
    for (int r = tid; r < PRE_N; r += 1024, k++) rv[k] = u.s[r];
    __syncthreads();                       // all s[] reads done before slot16 writes
    k = 0;
    for (int r = tid; r < PRE_N; r += 1024, k++) {
      u64 key = rv[k];
      u32 desc = (u32)(key >> 31);         // padding ~0 -> 0xFFFFFFFF
      bool valid = desc < 0xFF800000u;     // score > -inf
      if (!valid) atomicMin(&sh_nv, r);
      u.n.slot16[r] = valid ? (u16)(key & 0x1FFFu) : (u16)0xFFFF;
    }
  }
  __syncthreads();
  // ---- NMS ----
  int lane = tid & 63;
  int wv = tid >> 6;
  int nvalid = sh_nv;
  if (nvalid > PRE_N) nvalid = PRE_N;
  const float4* bp = boxsel + (size_t)img * SEL_CAP;
  if (tid < 64) {
    float4 c = make_float4(0.f, 0.f, 0.f, 0.f);
    if (tid < nvalid) { u16 sl = u.n.slot16[tid]; c = bp[sl]; }
    u.n.cb[0][tid] = c;
    float A = (c.z - c.x + 1.0f) * (c.w - c.y + 1.0f);
    u.n.car[0][tid] = A;
    u.n.cint[0][tid] = (int)rintf(8.0f * log2f(A));
  } else if (tid < 128) {
    u.n.wcol[0][tid - 64] = 0;
  } else if (tid < 128 + NMS_W) {
    u.n.supw[0][tid - 128] = 0;
  }
  __syncthreads();
  int pb = 0;
  for (int base = 0; base < nvalid; base += 64, pb ^= 1) {
    int nk = sh_nkept;
    if (nk >= POST_N) break;
    int bn = nvalid - base; if (bn > 64) bn = 64;
    // ---- wave-1: issue next-batch gather EARLY (hides under phase A+B) ----
    float4 pfc = make_float4(0.f, 0.f, 0.f, 0.f);
    bool havepf = (wv == 1) && (base + 64 < nvalid);
    if (havepf) {
      int i = base + 64 + lane;
      if (i < nvalid) { u16 sl = u.n.slot16[i]; pfc = bp[sl]; }
    }
    // ---- phase A: vs-kept tests + within-batch column masks (no early exit) ----
    bool sup;
    u64 colpart = 0;
    {
      bool inb = lane < bn;
      sup = !inb;
      if (inb) {
        float4 C = u.n.cb[pb][lane];
        float A0 = u.n.car[pb][lane];
        int myc = u.n.cint[pb][lane];
        int nw = (nk + 7) >> 3;
        for (int jw = wv; jw < nw; jw += NMS_W) {
          u64 w = u.n.kcodeW[jw];
          int jbase = jw << 3;
          int jm = nk - jbase; if (jm > 8) jm = 8;
          for (int k = 0; k < jm; k++) {
            int d = (int)((w >> (k * 8)) & 0xFFu) - myc;
            if (d > 5 || d < -5) continue;          // conservative area-ratio gate
            int j = jbase + k;
            float4 K = u.n.kbox[j];
            float xx1 = fmaxf(K.x, C.x);
            float yy1 = fmaxf(K.y, C.y);
            float xx2 = fminf(K.z, C.z);
            float yy2 = fminf(K.w, C.w);
            float iw = fmaxf(0.0f, xx2 - xx1 + 1.0f);
            float ih = fmaxf(0.0f, yy2 - yy1 + 1.0f);
            float inter = iw * ih;
            float uni = (u.n.karea[j] + A0) - inter; // kept area first (ref order)
            sup = sup | iou_gt(inter, uni);
          }
        }
        // within-batch: candidate = lane (the LATER one), scan earlier i
        for (int i = wv; i < lane; i += NMS_W) {
          if (i >= bn) break;
          float Ai = u.n.car[pb][i];
          if (Ai <= 0.6999f * A0 || A0 <= 0.6999f * Ai) continue;
          float4 I4 = u.n.cb[pb][i];
          float xx1 = fmaxf(I4.x, C.x);
          float yy1 = fmaxf(I4.y, C.y);
          float xx2 = fminf(I4.z, C.z);
          float yy2 = fminf(I4.w, C.w);
          float iw = fmaxf(0.0f, xx2 - xx1 + 1.0f);
          float ih = fmaxf(0.0f, yy2 - yy1 + 1.0f);
          float inter = iw * ih;
          float uni = (Ai + A0) - inter;            // earlier (i) area first
          if (iou_gt(inter, uni)) colpart |= 1ULL << i;
        }
      }
    }
    u64 bm = __ballot(sup);
    if (lane == 0) u.n.supw[pb][wv] = bm;
    if (colpart) atomicOr(&u.n.wcol[pb][lane], colpart);
    // wave-1: land prefetch into the other buffer (no reader until next iter)
    if (havepf) {
      u.n.cb[pb ^ 1][lane] = pfc;
      float A = (pfc.z - pfc.x + 1.0f) * (pfc.w - pfc.y + 1.0f);
      u.n.car[pb ^ 1][lane] = A;
      u.n.cint[pb ^ 1][lane] = (int)rintf(8.0f * log2f(A));
    }
    __syncthreads();
    // ---- phase B (wave 0: fixpoint greedy) | wave 2: zero next masks ----
    if (wv == 0) {
      u64 so = (lane < NMS_W) ? u.n.supw[pb][lane] : 0ULL;
      so |= __shfl_xor(so, 1);
      so |= __shfl_xor(so, 2);
      so |= __shfl_xor(so, 4);
      so |= __shfl_xor(so, 8);
      so = __shfl(so, 0);
      u64 validm = (bn >= 64) ? ~0ULL : ((1ULL << bn) - 1ULL);
      u64 colm = u.n.wcol[pb][lane];             // earlier-index suppressors of ME
      u64 live = validm & ~so;
      // Jacobi fixpoint == serial greedy (deps strictly earlier-index):
      // K_{t+1} = live & ~{c : K_t ∩ colm_c ≠ ∅}; converges in ≤ depth iters.
      u64 K = live;
      while (true) {
        u64 supk = __ballot((K & colm) != 0ULL);
        u64 Kn = live & ~supk;
        if (Kn == K) break;
        K = Kn;
      }
      int m = POST_N - nk;
      int kc = (int)__popcll(K);
      if (kc > m) {
        // greedy prefix property: first m keeps of the batch == greedy's m
        for (int e = kc - m; e > 0; --e) K &= ~(1ULL << (63 - __clzll((long long)K)));
        kc = m;
      }
      int cnt = nk + kc;
      if ((K >> lane) & 1ULL) {
        int rank = nk + (int)__popcll(K & ((1ULL << lane) - 1ULL));
        float4 C = u.n.cb[pb][lane];
        u.n.kbox[rank] = C;
        u.n.karea[rank] = u.n.car[pb][lane];
        ((unsigned char*)u.n.kcodeW)[rank] = (unsigned char)u.n.cint[pb][lane];
        float* o = out + ((size_t)img * POST_N + rank) * 5;
        o[0] = (float)img; o[1] = C.x; o[2] = C.y; o[3] = C.z; o[4] = C.w;
      }
      if (lane == 0) sh_nkept = cnt;
    } else if (wv == 2) {
      u.n.wcol[pb ^ 1][lane] = 0;
      if (lane < NMS_W) u.n.supw[pb ^ 1][lane] = 0;
    }
    __syncthreads();
  }
  int fk = sh_nkept;
  for (int r = fk + tid; r < POST_N; r += NMS_W * 64) {
    float* o = out + ((size_t)img * POST_N + r) * 5;
    o[0] = (float)img; o[1] = 0.f; o[2] = 0.f; o[3] = 0.f; o[4] = 0.f;
  }
}

extern "C" void kernel_launch(void* const* d_in, const int* in_sizes, int n_in,
                              void* d_out, int out_size, void* d_ws, size_t ws_size,
                              hipStream_t stream) {
  const float* sm   = (const float*)d_in[0];
  const float* bd   = (const float*)d_in[1];
  const float* info = (const float*)d_in[2];
  float* out = (float*)d_out;
  char* ws = (char*)d_ws;

  size_t off = 0;
  auto alloc = [&](size_t bytes) { size_t o = off; off += (bytes + 255) & ~(size_t)255; return o; };
  u32* keys     = (u32*)(ws + alloc((size_t)NBATCH * NPB * 4));        // ~14.7 MB
  size_t off_hist = alloc((size_t)NBATCH * UNI_BINS * 4);              // 64 KB
  u32* hist     = (u32*)(ws + off_hist);
  u32* selcnt   = (u32*)(ws + alloc(NBATCH * 4));                      // adjacent to hist
  size_t zero_end = off;
  u64* sel      = (u64*)(ws + alloc((size_t)NBATCH * SEL_CAP * 8));    // 1 MB
  float4* boxsel= (float4*)(ws + alloc((size_t)NBATCH * SEL_CAP * 16));// 2 MB
  (void)ws_size; (void)in_sizes; (void)n_in; (void)out_size;

  hipMemsetAsync(ws + off_hist, 0, zero_end - off_hist, stream);       // hist + selcnt
  hipLaunchKernelGGL(k_scores_hist, dim3(720), dim3(256), 0, stream, sm, bd, info, keys, hist);
  hipLaunchKernelGGL(k_compact, dim3(60, 16), dim3(256), 0, stream, keys, hist, selcnt, sel, bd, info, boxsel);
  hipLaunchKernelGGL(k_sort1, dim3(SEL_CAP / CHUNK, 16), dim3(256), 0, stream, sel, selcnt);
  hipLaunchKernelGGL(k_sort2nms, dim3(16), dim3(1024), 0, stream, sel, selcnt, boxsel, out);
}

// Round 9
// 190.161 us; speedup vs baseline: 1.0511x; 1.0273x over previous
//
#include <hip/hip_runtime.h>
#include <cstdint>
#include <cstddef>

typedef unsigned int u32;
typedef unsigned short u16;
typedef unsigned long long u64;

#define NBATCH 16
#define NA 9
#define HF 160
#define WF 160
#define HWC (HF*WF)          // 25600
#define NPB (NA*HWC)         // 230400 anchors per image
#define PRE_N 6000
#define POST_N 300
#define SEL_CAP 8192
#define NBIN 2048            // fallback radix bins
#define UNI_BINS 1024        // uniform score bins (2^10; s*1024 and q/1024 are exact fp32)
#define HSLICES 45           // per-image hist slices (one per hist block)
#define NMS_W 16             // waves in fused sort2+nms (1024 threads)
#define CHUNK 512            // sort1 chunk (16 chunks/img x 16 img = 256 blocks = full chip)

// [r8 note: this is a RESUBMIT of the r8 kernel — round 8 hit a GPU
//  acquisition timeout and never benched; the slice-hist hypothesis is
//  still unmeasured.]
// [r7 lesson: fusing select into compact (960 redundant hist scans) cost more
//  than the dispatch boundary it saved (+3.6 us). Dedicated 16-block select is
//  the measured-good structure.]
// [r6 lesson: hist wants 720 blocks x 20 keys/thread; wider grids make the
//  per-block LDS zero/flush dominate. Occupancy was never hist's limiter.]
// [r4 lesson: no done-ticket fences — 720 device-scope releases serialize L2.]
// [r1 lesson: never collapse a wide grid into the 16-block merge kernel.]
// [r8: memset dispatch eliminated — hist writes per-block SLICES (plain
//  uint4 stores, every element written -> no zero, no atomics); select sums
//  the 45 slices and zeroes selcnt for compact.]

// Anchor constants derived exactly from generate_anchors(16,[0.5,1,2],[8,16,32]):
// all anchors have center (8,8) at cell (0,0); only w/h differ.
__constant__ float c_AW[9] = {184.f,368.f,736.f,128.f,256.f,512.f,88.f,176.f,352.f};
__constant__ float c_AH[9] = {96.f,192.f,384.f,128.f,256.f,512.f,176.f,352.f,704.f};

// Shared math core so the keep decision and box decode use byte-identical
// expressions (fp-contract applied identically).
__device__ __forceinline__ void box_core(
    float d0, float d1, float d2, float d3, int a, int x, int y,
    float imH, float imW, float ms,
    float& x1, float& y1, float& x2, float& y2, bool& keep)
{
  float aw = c_AW[a], ah = c_AH[a];
  float acx = (float)x * 16.0f + 8.0f;
  float acy = (float)y * 16.0f + 8.0f;
  float pcx = d0 * aw + acx;
  float pcy = d1 * ah + acy;
  float pw  = expf(d2) * aw;
  float ph  = expf(d3) * ah;
  x1 = fminf(fmaxf(pcx - 0.5f * pw, 0.0f), imW - 1.0f);
  y1 = fminf(fmaxf(pcy - 0.5f * ph, 0.0f), imH - 1.0f);
  x2 = fminf(fmaxf(pcx + 0.5f * pw, 0.0f), imW - 1.0f);
  y2 = fminf(fmaxf(pcy + 0.5f * ph, 0.0f), imH - 1.0f);
  keep = ((x2 - x1 + 1.0f) >= ms) && ((y2 - y1 + 1.0f) >= ms);
}

__device__ __forceinline__ void box_from_deltas(
    const float* __restrict__ bd, int b, int a, int pos,
    float imH, float imW, float ms,
    float& x1, float& y1, float& x2, float& y2, bool& keep)
{
  int y = pos / WF;
  int x = pos - y * WF;
  size_t base = ((size_t)(b * 4 * NA) + 4 * a) * HWC + (size_t)pos;
  float d0 = bd[base];
  float d1 = bd[base + HWC];
  float d2 = bd[base + 2 * HWC];
  float d3 = bd[base + 3 * HWC];
  box_core(d0, d1, d2, d3, a, x, y, imH, imW, ms, x1, y1, x2, y2, keep);
}

__device__ __forceinline__ u32 desc_enc(float s) {
  u32 su = __float_as_uint(s);
  u32 asc = (su & 0x80000000u) ? ~su : (su | 0x80000000u);
  return ~asc;
}

// Exact divide-free IoU>0.7 test: fmaf sign is exact outside a relative 1e-6
// band; inside the band fall back to the IEEE divide (same operand order as
// the reference), so the decision is bit-identical to the reference.
__device__ __forceinline__ bool iou_gt(float inter, float uni) {
  float ss = fmaf(0.7f, uni, -inter);
  if (fabsf(ss) <= uni * 1e-6f) return (inter / uni > 0.7f);
  return ss < 0.0f;
}

// keys (4B desc; flat idx derivable from array position) + per-block hist
// SLICE. 720 blocks x 20 keys/thread (proven shape). The slice is written
// with plain uint4 stores (4 KB contiguous, every element) -> no global
// atomics, no pre-zeroing, no memset dispatch.
__global__ void __launch_bounds__(256) k_scores_hist(
    const float* __restrict__ sm, const float* __restrict__ bd,
    const float* __restrict__ info, u32* __restrict__ keys, u32* __restrict__ hist) {
  __shared__ u32 lh[UNI_BINS];
  int img   = blockIdx.x / HSLICES;
  int rem   = blockIdx.x - img * HSLICES;
  int a     = rem / 5;
  int chunk = rem - a * 5;
  int tid = threadIdx.x;
  for (int i = tid; i < UNI_BINS; i += 256) lh[i] = 0;
  __syncthreads();
  float imH = info[img*3+0], imW = info[img*3+1], ms = 16.0f * info[img*3+2];
  const float* sp = sm + ((size_t)(img * 2 * NA) + NA + a) * HWC;
  const float* dp = bd + ((size_t)(img * 4 * NA) + 4 * a) * HWC;
  u32* kp = keys + (size_t)img * NPB + (size_t)a * HWC;
  for (int j = 0; j < 5; j++) {
    int pos0 = (chunk * 1280 + j * 256 + tid) * 4;
    float4 s4  = *(const float4*)&sp[pos0];
    float4 q0  = *(const float4*)&dp[pos0];
    float4 q1  = *(const float4*)&dp[HWC + pos0];
    float4 q2  = *(const float4*)&dp[2*HWC + pos0];
    float4 q3  = *(const float4*)&dp[3*HWC + pos0];
    float sv[4] = {s4.x, s4.y, s4.z, s4.w};
    float v0[4] = {q0.x, q0.y, q0.z, q0.w};
    float v1[4] = {q1.x, q1.y, q1.z, q1.w};
    float v2[4] = {q2.x, q2.y, q2.z, q2.w};
    float v3[4] = {q3.x, q3.y, q3.z, q3.w};
    u32 kq[4];
    #pragma unroll
    for (int e = 0; e < 4; e++) {
      int pos = pos0 + e;
      int y = pos / WF;
      int x = pos - y * WF;
      float x1, y1, x2, y2; bool keep;
      box_core(v0[e], v1[e], v2[e], v3[e], a, x, y, imH, imW, ms, x1, y1, x2, y2, keep);
      float s = sv[e];
      if (!keep) s = __uint_as_float(0xFF800000u);  // -inf
      kq[e] = desc_enc(s);
      int q = (int)floorf(s * (float)UNI_BINS);
      q = q < 0 ? 0 : (q > UNI_BINS - 1 ? UNI_BINS - 1 : q);
      atomicAdd(&lh[(UNI_BINS - 1) - q], 1u);
    }
    *(uint4*)&kp[pos0] = make_uint4(kq[0], kq[1], kq[2], kq[3]);
  }
  __syncthreads();
  u32* gh = hist + ((size_t)img * HSLICES + rem) * UNI_BINS;
  ((uint4*)gh)[tid] = make_uint4(lh[4*tid], lh[4*tid+1], lh[4*tid+2], lh[4*tid+3]);
}

// Select threshold (16 blocks, one per image): sum the 45 per-block slices
// (L2-resident), then 1-pass exact boundary select; radix fallback over
// reconstructed 64-bit keys for pathological ties. Also zeroes selcnt[img]
// (dispatch boundary orders it before compact).
__global__ void __launch_bounds__(256) k_select(
    const u32* __restrict__ keys, const u32* __restrict__ hist,
    u64* __restrict__ thresh_arr, u32* __restrict__ selcnt) {
  int img = blockIdx.x, tid = threadIdx.x;
  __shared__ u32 sc[256];
  __shared__ u32 lh[NBIN];
  __shared__ u64 sh_thresh;
  __shared__ int sh_state;
  __shared__ u64 sh_prefix;
  __shared__ u32 sh_kth;
  if (tid == 0) selcnt[img] = 0;
  const u32* gh = hist + (size_t)img * HSLICES * UNI_BINS;
  u32 loc[4] = {0, 0, 0, 0};
  for (int s = 0; s < HSLICES; s++) {
    uint4 v = ((const uint4*)(gh + s * UNI_BINS))[tid];
    loc[0] += v.x; loc[1] += v.y; loc[2] += v.z; loc[3] += v.w;
  }
  u32 tot = loc[0] + loc[1] + loc[2] + loc[3];
  if (tid == 0) { sh_state = 0; sh_prefix = 0; sh_kth = PRE_N; }
  sc[tid] = tot;
  __syncthreads();
  for (int off = 1; off < 256; off <<= 1) {
    u32 v = sc[tid]; u32 a = (tid >= off) ? sc[tid - off] : 0u;
    __syncthreads(); sc[tid] = v + a; __syncthreads();
  }
  u32 incl = sc[tid], excl = incl - tot;
  if (PRE_N > excl && PRE_N <= incl) {
    u32 run = excl;
    #pragma unroll
    for (int j = 0; j < 4; j++) {
      run += loc[j];
      if (run >= PRE_N) {
        int b = tid * 4 + j;
        if (b < UNI_BINS - 1 && run <= SEL_CAP) {
          float sb = (float)(UNI_BINS - 1 - b) * (1.0f / (float)UNI_BINS);
          sh_thresh = ((u64)desc_enc(sb) << 32) | 0xFFFFFFFFull;
          sh_state = 1;
        }
        break;
      }
    }
  }
  __syncthreads();
  if (!sh_state) {
    const u32* kp = keys + (size_t)img * NPB;
    const int shifts[6] = {53, 42, 31, 20, 9, 0};
    const int widths[6] = {11, 11, 11, 11, 11, 9};
    for (int p = 0; p < 6; p++) {
      if (sh_state) break;
      for (int i = tid; i < NBIN; i += 256) lh[i] = 0;
      __syncthreads();
      u64 prefix = sh_prefix; u32 kth = sh_kth;
      int shift = shifts[p], width = widths[p];
      u32 nb = 1u << width;
      int hs = shift + width;
      for (int i = tid; i < NPB; i += 256) {
        int ia = i / HWC;
        int pos = i - ia * HWC;
        u64 key = ((u64)kp[i] << 32) | (u64)(u32)(pos * NA + ia);
        bool m = (p == 0) || ((key >> hs) == prefix);
        if (m) atomicAdd(&lh[(u32)(key >> shift) & (nb - 1u)], 1u);
      }
      __syncthreads();
      u32 l2[8]; u32 t2 = 0;
      #pragma unroll
      for (int j = 0; j < 8; j++) {
        u32 b = (u32)(tid * 8 + j);
        u32 v = (b < nb) ? lh[b] : 0u;
        l2[j] = v; t2 += v;
      }
      sc[tid] = t2; __syncthreads();
      for (int off = 1; off < 256; off <<= 1) {
        u32 v = sc[tid]; u32 a = (tid >= off) ? sc[tid - off] : 0u;
        __syncthreads(); sc[tid] = v + a; __syncthreads();
      }
      u32 incl2 = sc[tid], excl2 = incl2 - t2;
      if (kth > excl2 && kth <= incl2) {
        u32 run = excl2;
        for (int j = 0; j < 8; j++) {
          run += l2[j];
          if (run >= kth) {
            u32 bin = (u32)(tid * 8 + j);
            u32 below = run - l2[j];
            u32 cnt = l2[j];
            u32 knew = kth - below;
            u64 pfull = (prefix << width) | (u64)bin;
            u32 M = (u32)PRE_N - knew + cnt;
            if (M <= SEL_CAP) {
              u64 lowmask = (shift > 0) ? ((1ULL << shift) - 1ULL) : 0ULL;
              sh_thresh = (pfull << shift) | lowmask;
              sh_state = 1;
            } else {
              sh_prefix = pfull; sh_kth = knew;
            }
            break;
          }
        }
      }
      __syncthreads();
    }
  }
  if (tid == 0) thresh_arr[img] = sh_thresh;
}

// Block-aggregated compaction + box decode for selected keys (r5-measured
// body, unchanged). Sort element:
// [desc:32 (bits 62..31) | anchoridx:18 (30..13) | slot:13 (12..0)].
__global__ void __launch_bounds__(256) k_compact(
    const u32* __restrict__ keys, const u64* __restrict__ thresh,
    u32* __restrict__ selcnt, u64* __restrict__ sel,
    const float* __restrict__ bd, const float* __restrict__ info,
    float4* __restrict__ boxsel) {
  int img = blockIdx.y;
  int tid = threadIdx.x;
  u64 T = thresh[img];
  int t0 = blockIdx.x * 3840;
  const u32* kp = keys + (size_t)img * NPB + t0;
  u64 fk[15];
  u32 mycnt = 0;
  #pragma unroll
  for (int j = 0; j < 15; j++) {
    int t = t0 + j * 256 + tid;
    u32 d = kp[j * 256 + tid];
    int a = t / HWC;
    int pos = t - a * HWC;
    u64 key = ((u64)d << 32) | (u64)(u32)(pos * NA + a);
    fk[j] = key;
    if (key <= T) mycnt++;
  }
  __shared__ u32 sc[256];
  __shared__ u32 sbase;
  sc[tid] = mycnt;
  __syncthreads();
  for (int off = 1; off < 256; off <<= 1) {
    u32 v = sc[tid];
    u32 add = (tid >= off) ? sc[tid - off] : 0u;
    __syncthreads();
    sc[tid] = v + add;
    __syncthreads();
  }
  if (tid == 255 && sc[255] > 0) sbase = atomicAdd(&selcnt[img], sc[255]);
  __syncthreads();
  if (mycnt == 0) return;
  u32 myoff = sbase + sc[tid] - mycnt;
  u64* sp = sel + (size_t)img * SEL_CAP;
  float4* bp = boxsel + (size_t)img * SEL_CAP;
  float imH = info[img*3+0], imW = info[img*3+1], ms = 16.0f * info[img*3+2];
  u32 c = 0;
  #pragma unroll
  for (int j = 0; j < 15; j++) {
    u64 key = fk[j];
    if (key <= T) {
      u32 p = myoff + c;
      if (p < SEL_CAP) {
        u32 desc = (u32)(key >> 32);
        u32 idx = (u32)key;
        sp[p] = ((u64)desc << 31) | ((u64)idx << 13) | (u64)p;
        int a = (int)(idx % NA);
        int pos = (int)(idx / NA);
        float x1, y1, x2, y2; bool keep;
        box_from_deltas(bd, img, a, pos, imH, imW, ms, x1, y1, x2, y2, keep);
        bp[p] = make_float4(x1, y1, x2, y2);
      }
      c++;
    }
  }
}

// Stage 1: sort each 512-key chunk ascending in LDS. 16 chunks/image x 16
// images = 256 blocks -> full-chip parallelism.
__global__ void __launch_bounds__(256) k_sort1(u64* __restrict__ sel, const u32* __restrict__ selcnt) {
  __shared__ u64 s[CHUNK];
  int img = blockIdx.y, c = blockIdx.x, tid = threadIdx.x;
  u32 cnt = selcnt[img]; if (cnt > SEL_CAP) cnt = SEL_CAP;
  u64* sp = sel + (size_t)img * SEL_CAP + (size_t)c * CHUNK;
  int gbase = c * CHUNK;
  for (int i = tid; i < CHUNK; i += 256) s[i] = ((u32)(gbase + i) < cnt) ? sp[i] : ~0ULL;
  __syncthreads();
  for (int k = 2; k <= CHUNK; k <<= 1) {
    for (int j = k >> 1; j > 0; j >>= 1) {
      for (int i = tid; i < CHUNK; i += 256) {
        int p = i ^ j;
        if (p > i) {
          u64 a = s[i], b = s[p];
          bool up = ((i & k) == 0);
          if (up ? (a > b) : (a < b)) { s[i] = b; s[p] = a; }
        }
      }
      __syncthreads();
    }
  }
  for (int i = tid; i < CHUNK; i += 256) sp[i] = s[i];
}

// Fused stage 2 + NMS (16 blocks x 1024 threads; fusion loses no parallelism).
// (a) final merge level prunes threads with d0 >= PRE_N (output unused);
// (b) phase-B Jacobi fixpoint == serial greedy (provably identical keep set);
// (c) wave-1 next-batch prefetch issued at phase-A start.
__global__ void __launch_bounds__(1024) k_sort2nms(
    const u64* __restrict__ sel, const u32* __restrict__ selcnt,
    const float4* __restrict__ boxsel, float* __restrict__ out) {
  union SB {
    u64 s[SEL_CAP];                        // 64 KiB (merge phase)
    struct {                               // NMS phase (~23 KiB, aliases s)
      u16 slot16[PRE_N + 64];              // rank -> boxsel slot (0xFFFF = invalid)
      float4 kbox[POST_N];
      float karea[POST_N];
      u64 kcodeW[(POST_N + 7) / 8];
      float4 cb[2][64];
      float car[2][64];
      int cint[2][64];
      u64 wcol[2][64];
      u64 supw[2][NMS_W];
    } n;
  };
  __shared__ SB u;
  __shared__ int sh_nv;
  __shared__ int sh_nkept;
  int img = blockIdx.x;
  int tid = threadIdx.x;
  const u64* sp = sel + (size_t)img * SEL_CAP;
  if (tid == 0) { sh_nv = PRE_N; sh_nkept = 0; }
  for (int i = tid; i < SEL_CAP; i += 1024) u.s[i] = sp[i];
  __syncthreads();
  // ---- merge 16 runs of 512 -> 8192 (4 merge-path levels) ----
  int d0 = tid * 8;
  for (int L = CHUNK; L < SEL_CAP; L <<= 1) {
    bool act = (2 * L < SEL_CAP) || (d0 < PRE_N);   // final-level prune
    u64 o[8];
    if (act) {
      int pairBase = d0 & ~(2 * L - 1);
      int d = d0 - pairBase;
      const u64* A = u.s + pairBase;
      const u64* B = u.s + pairBase + L;
      int lo = d - L; if (lo < 0) lo = 0;
      int hi = (d < L) ? d : L;
      while (lo < hi) {
        int mid = (lo + hi) >> 1;
        if (A[mid] <= B[d - 1 - mid]) lo = mid + 1; else hi = mid;
      }
      int ia = lo, ib = d - lo;
      #pragma unroll
      for (int k = 0; k < 8; k++) {
        bool ta = (ib >= L) || (ia < L && A[ia] <= B[ib]);
        o[k] = ta ? A[ia++] : B[ib++];
      }
    }
    __syncthreads();
    if (act) {
      #pragma unroll
      for (int k = 0; k < 8; k++) u.s[d0 + k] = o[k];
    }
    __syncthreads();
  }
  // ---- rank -> slot conversion (register-staged to dodge union aliasing) ----
  u64 rv[6];
  {
    int k = 0;
    for (int r = tid; r < PRE_N; r += 1024, k++) rv[k] = u.s[r];
    __syncthreads();                       // all s[] reads done before slot16 writes
    k = 0;
    for (int r = tid; r < PRE_N; r += 1024, k++) {
      u64 key = rv[k];
      u32 desc = (u32)(key >> 31);         // padding ~0 -> 0xFFFFFFFF
      bool valid = desc < 0xFF800000u;     // score > -inf
      if (!valid) atomicMin(&sh_nv, r);
      u.n.slot16[r] = valid ? (u16)(key & 0x1FFFu) : (u16)0xFFFF;
    }
  }
  __syncthreads();
  // ---- NMS ----
  int lane = tid & 63;
  int wv = tid >> 6;
  int nvalid = sh_nv;
  if (nvalid > PRE_N) nvalid = PRE_N;
  const float4* bp = boxsel + (size_t)img * SEL_CAP;
  if (tid < 64) {
    float4 c = make_float4(0.f, 0.f, 0.f, 0.f);
    if (tid < nvalid) { u16 sl = u.n.slot16[tid]; c = bp[sl]; }
    u.n.cb[0][tid] = c;
    float A = (c.z - c.x + 1.0f) * (c.w - c.y + 1.0f);
    u.n.car[0][tid] = A;
    u.n.cint[0][tid] = (int)rintf(8.0f * log2f(A));
  } else if (tid < 128) {
    u.n.wcol[0][tid - 64] = 0;
  } else if (tid < 128 + NMS_W) {
    u.n.supw[0][tid - 128] = 0;
  }
  __syncthreads();
  int pb = 0;
  for (int base = 0; base < nvalid; base += 64, pb ^= 1) {
    int nk = sh_nkept;
    if (nk >= POST_N) break;
    int bn = nvalid - base; if (bn > 64) bn = 64;
    // ---- wave-1: issue next-batch gather EARLY (hides under phase A+B) ----
    float4 pfc = make_float4(0.f, 0.f, 0.f, 0.f);
    bool havepf = (wv == 1) && (base + 64 < nvalid);
    if (havepf) {
      int i = base + 64 + lane;
      if (i < nvalid) { u16 sl = u.n.slot16[i]; pfc = bp[sl]; }
    }
    // ---- phase A: vs-kept tests + within-batch column masks (no early exit) ----
    bool sup;
    u64 colpart = 0;
    {
      bool inb = lane < bn;
      sup = !inb;
      if (inb) {
        float4 C = u.n.cb[pb][lane];
        float A0 = u.n.car[pb][lane];
        int myc = u.n.cint[pb][lane];
        int nw = (nk + 7) >> 3;
        for (int jw = wv; jw < nw; jw += NMS_W) {
          u64 w = u.n.kcodeW[jw];
          int jbase = jw << 3;
          int jm = nk - jbase; if (jm > 8) jm = 8;
          for (int k = 0; k < jm; k++) {
            int d = (int)((w >> (k * 8)) & 0xFFu) - myc;
            if (d > 5 || d < -5) continue;          // conservative area-ratio gate
            int j = jbase + k;
            float4 K = u.n.kbox[j];
            float xx1 = fmaxf(K.x, C.x);
            float yy1 = fmaxf(K.y, C.y);
            float xx2 = fminf(K.z, C.z);
            float yy2 = fminf(K.w, C.w);
            float iw = fmaxf(0.0f, xx2 - xx1 + 1.0f);
            float ih = fmaxf(0.0f, yy2 - yy1 + 1.0f);
            float inter = iw * ih;
            float uni = (u.n.karea[j] + A0) - inter; // kept area first (ref order)
            sup = sup | iou_gt(inter, uni);
          }
        }
        // within-batch: candidate = lane (the LATER one), scan earlier i
        for (int i = wv; i < lane; i += NMS_W) {
          if (i >= bn) break;
          float Ai = u.n.car[pb][i];
          if (Ai <= 0.6999f * A0 || A0 <= 0.6999f * Ai) continue;
          float4 I4 = u.n.cb[pb][i];
          float xx1 = fmaxf(I4.x, C.x);
          float yy1 = fmaxf(I4.y, C.y);
          float xx2 = fminf(I4.z, C.z);
          float yy2 = fminf(I4.w, C.w);
          float iw = fmaxf(0.0f, xx2 - xx1 + 1.0f);
          float ih = fmaxf(0.0f, yy2 - yy1 + 1.0f);
          float inter = iw * ih;
          float uni = (Ai + A0) - inter;            // earlier (i) area first
          if (iou_gt(inter, uni)) colpart |= 1ULL << i;
        }
      }
    }
    u64 bm = __ballot(sup);
    if (lane == 0) u.n.supw[pb][wv] = bm;
    if (colpart) atomicOr(&u.n.wcol[pb][lane], colpart);
    // wave-1: land prefetch into the other buffer (no reader until next iter)
    if (havepf) {
      u.n.cb[pb ^ 1][lane] = pfc;
      float A = (pfc.z - pfc.x + 1.0f) * (pfc.w - pfc.y + 1.0f);
      u.n.car[pb ^ 1][lane] = A;
      u.n.cint[pb ^ 1][lane] = (int)rintf(8.0f * log2f(A));
    }
    __syncthreads();
    // ---- phase B (wave 0: fixpoint greedy) | wave 2: zero next masks ----
    if (wv == 0) {
      u64 so = (lane < NMS_W) ? u.n.supw[pb][lane] : 0ULL;
      so |= __shfl_xor(so, 1);
      so |= __shfl_xor(so, 2);
      so |= __shfl_xor(so, 4);
      so |= __shfl_xor(so, 8);
      so = __shfl(so, 0);
      u64 validm = (bn >= 64) ? ~0ULL : ((1ULL << bn) - 1ULL);
      u64 colm = u.n.wcol[pb][lane];             // earlier-index suppressors of ME
      u64 live = validm & ~so;
      // Jacobi fixpoint == serial greedy (deps strictly earlier-index):
      // K_{t+1} = live & ~{c : K_t ∩ colm_c ≠ ∅}; converges in ≤ depth iters.
      u64 K = live;
      while (true) {
        u64 supk = __ballot((K & colm) != 0ULL);
        u64 Kn = live & ~supk;
        if (Kn == K) break;
        K = Kn;
      }
      int m = POST_N - nk;
      int kc = (int)__popcll(K);
      if (kc > m) {
        // greedy prefix property: first m keeps of the batch == greedy's m
        for (int e = kc - m; e > 0; --e) K &= ~(1ULL << (63 - __clzll((long long)K)));
        kc = m;
      }
      int cnt = nk + kc;
      if ((K >> lane) & 1ULL) {
        int rank = nk + (int)__popcll(K & ((1ULL << lane) - 1ULL));
        float4 C = u.n.cb[pb][lane];
        u.n.kbox[rank] = C;
        u.n.karea[rank] = u.n.car[pb][lane];
        ((unsigned char*)u.n.kcodeW)[rank] = (unsigned char)u.n.cint[pb][lane];
        float* o = out + ((size_t)img * POST_N + rank) * 5;
        o[0] = (float)img; o[1] = C.x; o[2] = C.y; o[3] = C.z; o[4] = C.w;
      }
      if (lane == 0) sh_nkept = cnt;
    } else if (wv == 2) {
      u.n.wcol[pb ^ 1][lane] = 0;
      if (lane < NMS_W) u.n.supw[pb ^ 1][lane] = 0;
    }
    __syncthreads();
  }
  int fk = sh_nkept;
  for (int r = fk + tid; r < POST_N; r += NMS_W * 64) {
    float* o = out + ((size_t)img * POST_N + r) * 5;
    o[0] = (float)img; o[1] = 0.f; o[2] = 0.f; o[3] = 0.f; o[4] = 0.f;
  }
}

extern "C" void kernel_launch(void* const* d_in, const int* in_sizes, int n_in,
                              void* d_out, int out_size, void* d_ws, size_t ws_size,
                              hipStream_t stream) {
  const float* sm   = (const float*)d_in[0];
  const float* bd   = (const float*)d_in[1];
  const float* info = (const float*)d_in[2];
  float* out = (float*)d_out;
  char* ws = (char*)d_ws;

  size_t off = 0;
  auto alloc = [&](size_t bytes) { size_t o = off; off += (bytes + 255) & ~(size_t)255; return o; };
  u32* keys     = (u32*)(ws + alloc((size_t)NBATCH * NPB * 4));        // ~14.7 MB
  u32* hist     = (u32*)(ws + alloc((size_t)NBATCH * HSLICES * UNI_BINS * 4)); // 2.95 MB slices
  u32* selcnt   = (u32*)(ws + alloc(NBATCH * 4));
  u64* thresh   = (u64*)(ws + alloc(NBATCH * 8));
  u64* sel      = (u64*)(ws + alloc((size_t)NBATCH * SEL_CAP * 8));    // 1 MB
  float4* boxsel= (float4*)(ws + alloc((size_t)NBATCH * SEL_CAP * 16));// 2 MB
  (void)ws_size; (void)in_sizes; (void)n_in; (void)out_size;

  hipLaunchKernelGGL(k_scores_hist, dim3(NBATCH * HSLICES), dim3(256), 0, stream, sm, bd, info, keys, hist);
  hipLaunchKernelGGL(k_select, dim3(16), dim3(256), 0, stream, keys, hist, thresh, selcnt);
  hipLaunchKernelGGL(k_compact, dim3(60, 16), dim3(256), 0, stream, keys, thresh, selcnt, sel, bd, info, boxsel);
  hipLaunchKernelGGL(k_sort1, dim3(SEL_CAP / CHUNK, 16), dim3(256), 0, stream, sel, selcnt);
  hipLaunchKernelGGL(k_sort2nms, dim3(16), dim3(1024), 0, stream, sel, selcnt, boxsel, out);
}